// Round 1
// baseline (915.474 us; speedup 1.0000x reference)
//
#include <hip/hip_runtime.h>

// GNN: 2-layer edge-coloured conv on MI355X.
// Layer l: out = act( X W_self^T + b + sum_c (A_c X) W_conv[c]^T )
// Strategy: build CSR over seg = c*N + dst once; fused gather+GEMM per layer
// (bf16 MFMA 16x16x32, fp32 accumulate). No large agg buffers.

#define NN 50000
#define EE 800000
#define DD 128
#define HH 256
#define CC 8
#define K1 1152   // C*D + D   (conv1 K + self1 K)
#define K2 2304   // C*H + H   (conv2 K + self2 K)

typedef unsigned short u16;
typedef __attribute__((ext_vector_type(8))) short s16x8;
typedef __attribute__((ext_vector_type(4))) float f32x4;

__device__ __forceinline__ float bf2f(short u) {
  return __uint_as_float(((unsigned)(u16)u) << 16);
}
__device__ __forceinline__ u16 f2bf(float f) {
  unsigned u = __float_as_uint(f);
  u = (u + 0x7FFFu + ((u >> 16) & 1u)) >> 16;   // RNE
  return (u16)u;
}

// ---------------- prep: casts + weight transpose to [o][k] bf16 ----------------

__global__ void k_castx(const float* __restrict__ x, u16* __restrict__ xb) {
  int i = blockIdx.x * 256 + threadIdx.x;
  if (i < NN * DD) xb[i] = f2bf(x[i]);
}

__global__ void k_wt1(const float* __restrict__ Wc1, const float* __restrict__ Ws1,
                      u16* __restrict__ Wt1) {
  int i = blockIdx.x * 256 + threadIdx.x;
  if (i >= HH * K1) return;
  int o = i / K1, k = i - o * K1;
  float v = (k < CC * DD) ? Wc1[(k >> 7) * (HH * DD) + o * DD + (k & 127)]
                          : Ws1[o * DD + (k - CC * DD)];
  Wt1[i] = f2bf(v);
}

__global__ void k_wt2(const float* __restrict__ Wc2, const float* __restrict__ Ws2,
                      u16* __restrict__ Wt2) {
  int i = blockIdx.x * 256 + threadIdx.x;
  if (i >= DD * K2) return;
  int o = i / K2, k = i - o * K2;
  float v = (k < CC * HH) ? Wc2[(k >> 8) * (DD * HH) + o * HH + (k & 255)]
                          : Ws2[o * HH + (k - CC * HH)];
  Wt2[i] = f2bf(v);
}

// ---------------- CSR build over seg = c*N + dst ----------------

__global__ void k_hist(const int* __restrict__ ei, const int* __restrict__ ec,
                       int* __restrict__ counts) {
  int e = blockIdx.x * 256 + threadIdx.x;
  if (e < EE) {
    int dst = ei[EE + e];
    int c = ec[e];
    atomicAdd(&counts[c * NN + dst], 1);
  }
}

// block-local exclusive scan + single atomic per block for the base.
// (segment ranges need not be globally ordered, just disjoint+contiguous)
__global__ void k_offsets(const int* __restrict__ counts, int* __restrict__ offs,
                          int* __restrict__ cursor, int* __restrict__ gcount) {
  __shared__ int lds[256];
  __shared__ int basesh;
  int tid = threadIdx.x;
  int i = blockIdx.x * 256 + tid;
  int c = (i < CC * NN) ? counts[i] : 0;
  lds[tid] = c;
  __syncthreads();
  int v = c;
  for (int s = 1; s < 256; s <<= 1) {
    int t = (tid >= s) ? lds[tid - s] : 0;
    __syncthreads();
    v += t;
    lds[tid] = v;
    __syncthreads();
  }
  if (tid == 255) basesh = atomicAdd(gcount, v);   // v = block total
  __syncthreads();
  int excl = basesh + v - c;
  if (i < CC * NN) { offs[i] = excl; cursor[i] = excl; }
}

__global__ void k_fill(const int* __restrict__ ei, const int* __restrict__ ec,
                       int* __restrict__ cursor, int* __restrict__ ssrc) {
  int e = blockIdx.x * 256 + threadIdx.x;
  if (e < EE) {
    int src = ei[e];
    int dst = ei[EE + e];
    int seg = ec[e] * NN + dst;
    int slot = atomicAdd(&cursor[seg], 1);
    ssrc[slot] = src;
  }
}

// ---------------- fused gather + GEMM layers ----------------
// Wave owns 16 rows x full output width. A-frag lane mapping: row = lane&15,
// k = 8*(lane>>4)+j. B-frag: col = lane&15, k = 8*(lane>>4)+j (B stored as Wt[o][k]).
// C/D: col = lane&15, row = (lane>>4)*4 + reg.

__global__ void __launch_bounds__(256) k_gemm1(
    const u16* __restrict__ xb, const u16* __restrict__ Wt,
    const float* __restrict__ b1,
    const int* __restrict__ offs, const int* __restrict__ cnts,
    const int* __restrict__ ssrc, u16* __restrict__ hb) {
  int wid = blockIdx.x * 4 + (threadIdx.x >> 6);
  int lane = threadIdx.x & 63;
  int r0 = wid * 16;
  if (r0 >= NN) return;                 // wave-uniform, no barriers in kernel
  int rs = lane & 15;
  int kg = lane >> 4;
  int row = r0 + rs;

  f32x4 acc[16];
#pragma unroll
  for (int i = 0; i < 16; i++)
#pragma unroll
    for (int q = 0; q < 4; q++) acc[i][q] = 0.f;

  for (int ks = 0; ks < 36; ++ks) {
    int k0 = ks * 32;
    s16x8 af;
    if (k0 < CC * DD) {
      // colour block: A row = sum of x[src] over edges of segment (c,row)
      int c = k0 >> 7;
      int f0 = (k0 & 127) + kg * 8;
      int seg = c * NN + row;
      int st = offs[seg];
      int cn = cnts[seg];
      float a[8];
#pragma unroll
      for (int q = 0; q < 8; q++) a[q] = 0.f;
      for (int j = 0; j < cn; ++j) {
        int s = ssrc[st + j];
        s16x8 v = *(const s16x8*)(xb + s * DD + f0);
#pragma unroll
        for (int q = 0; q < 8; q++) a[q] += bf2f(v[q]);
      }
#pragma unroll
      for (int q = 0; q < 8; q++) af[q] = (short)f2bf(a[q]);
    } else {
      // self block: A = x
      int f0 = (k0 - CC * DD) + kg * 8;
      af = *(const s16x8*)(xb + row * DD + f0);
    }
#pragma unroll
    for (int fc = 0; fc < 16; ++fc) {
      int col = fc * 16 + rs;
      s16x8 bfr = *(const s16x8*)(Wt + col * K1 + k0 + kg * 8);
      acc[fc] = __builtin_amdgcn_mfma_f32_16x16x32_bf16(af, bfr, acc[fc], 0, 0, 0);
    }
  }

#pragma unroll
  for (int fc = 0; fc < 16; ++fc) {
    int col = fc * 16 + rs;
    float bias = b1[col];
#pragma unroll
    for (int q = 0; q < 4; ++q) {
      float v = acc[fc][q] + bias;
      if (v < 0.f) v = 0.f;             // relu
      int rr = r0 + kg * 4 + q;
      hb[rr * HH + col] = f2bf(v);
    }
  }
}

__global__ void __launch_bounds__(256) k_gemm2(
    const u16* __restrict__ hb, const u16* __restrict__ Wt,
    const float* __restrict__ b2,
    const int* __restrict__ offs, const int* __restrict__ cnts,
    const int* __restrict__ ssrc, float* __restrict__ out) {
  int wid = blockIdx.x * 4 + (threadIdx.x >> 6);
  int lane = threadIdx.x & 63;
  int r0 = wid * 16;
  if (r0 >= NN) return;
  int rs = lane & 15;
  int kg = lane >> 4;
  int row = r0 + rs;

  f32x4 acc[8];
#pragma unroll
  for (int i = 0; i < 8; i++)
#pragma unroll
    for (int q = 0; q < 4; q++) acc[i][q] = 0.f;

  for (int ks = 0; ks < 72; ++ks) {
    int k0 = ks * 32;
    s16x8 af;
    if (k0 < CC * HH) {
      int c = k0 >> 8;
      int f0 = (k0 & 255) + kg * 8;
      int seg = c * NN + row;
      int st = offs[seg];
      int cn = cnts[seg];
      float a[8];
#pragma unroll
      for (int q = 0; q < 8; q++) a[q] = 0.f;
      for (int j = 0; j < cn; ++j) {
        int s = ssrc[st + j];
        s16x8 v = *(const s16x8*)(hb + s * HH + f0);
#pragma unroll
        for (int q = 0; q < 8; q++) a[q] += bf2f(v[q]);
      }
#pragma unroll
      for (int q = 0; q < 8; q++) af[q] = (short)f2bf(a[q]);
    } else {
      int f0 = (k0 - CC * HH) + kg * 8;
      af = *(const s16x8*)(hb + row * HH + f0);
    }
#pragma unroll
    for (int fc = 0; fc < 8; ++fc) {
      int col = fc * 16 + rs;
      s16x8 bfr = *(const s16x8*)(Wt + col * K2 + k0 + kg * 8);
      acc[fc] = __builtin_amdgcn_mfma_f32_16x16x32_bf16(af, bfr, acc[fc], 0, 0, 0);
    }
  }

#pragma unroll
  for (int fc = 0; fc < 8; ++fc) {
    int col = fc * 16 + rs;
    float bias = b2[col];
#pragma unroll
    for (int q = 0; q < 4; ++q) {
      float v = acc[fc][q] + bias;
      int rr = r0 + kg * 4 + q;
      out[rr * DD + col] = 1.f / (1.f + expf(10.f - v));   // sigmoid(v - 10)
    }
  }
}

// ---------------- launch ----------------

extern "C" void kernel_launch(void* const* d_in, const int* in_sizes, int n_in,
                              void* d_out, int out_size, void* d_ws, size_t ws_size,
                              hipStream_t stream) {
  const float* x   = (const float*)d_in[0];
  const int*   ei  = (const int*)d_in[1];   // [2,E] src row then dst row
  const int*   ec  = (const int*)d_in[2];   // [E]
  const float* Ws1 = (const float*)d_in[3]; // [H,D]
  const float* b1  = (const float*)d_in[4]; // [H]
  const float* Ws2 = (const float*)d_in[5]; // [D,H]
  const float* b2  = (const float*)d_in[6]; // [D]
  const float* Wc1 = (const float*)d_in[7]; // [C,H,D]
  const float* Wc2 = (const float*)d_in[8]; // [C,D,H]
  float* out = (float*)d_out;

  char* p = (char*)d_ws;
  u16* xb     = (u16*)p;  p += 12800000;   // x bf16 [N,128]
  u16* Wt1    = (u16*)p;  p += 589824;     // [256,1152] bf16
  u16* Wt2    = (u16*)p;  p += 589824;     // [128,2304] bf16
  int* counts = (int*)p;  p += 1600000;    // [C*N]
  int* gcount = (int*)p;  p += 256;        // global scan base
  int* offs   = (int*)p;  p += 1600000;    // [C*N]
  int* cursor = (int*)p;  p += 1600000;    // [C*N]
  int* ssrc   = (int*)p;  p += 3200000;    // [E] src per CSR slot
  u16* hb     = (u16*)p;  p += 25600000;   // h bf16 [N,256]

  hipMemsetAsync(counts, 0, 1600000 + 256, stream);  // counts + gcount

  k_castx<<<25000, 256, 0, stream>>>(x, xb);
  k_wt1<<<1152, 256, 0, stream>>>(Wc1, Ws1, Wt1);
  k_wt2<<<1152, 256, 0, stream>>>(Wc2, Ws2, Wt2);

  k_hist<<<3125, 256, 0, stream>>>(ei, ec, counts);
  k_offsets<<<1563, 256, 0, stream>>>(counts, offs, cursor, gcount);
  k_fill<<<3125, 256, 0, stream>>>(ei, ec, cursor, ssrc);

  k_gemm1<<<782, 256, 0, stream>>>(xb, Wt1, b1, offs, counts, ssrc, hb);
  k_gemm2<<<782, 256, 0, stream>>>(hb, Wt2, b2, offs, counts, ssrc, out);
}

// Round 4
// 801.513 us; speedup vs baseline: 1.1422x; 1.1422x over previous
//
#include <hip/hip_runtime.h>

// GNN: 2-layer edge-coloured conv on MI355X.
// Round 4 (= round 2 resubmit; two infra failures): hoist CSR gather out of
// the K-loop (one 128-feat slab per walk, 4 independent 16B loads/edge,
// 2-edge unroll), pack (off,cnt) as int2.

#define NN 50000
#define EE 800000
#define DD 128
#define HH 256
#define CC 8
#define K1 1152   // C*D + D
#define K2 2304   // C*H + H

typedef unsigned short u16;
typedef __attribute__((ext_vector_type(8))) short s16x8;
typedef __attribute__((ext_vector_type(4))) float f32x4;

__device__ __forceinline__ float bf2f(short u) {
  return __uint_as_float(((unsigned)(u16)u) << 16);
}
__device__ __forceinline__ u16 f2bf(float f) {
  unsigned u = __float_as_uint(f);
  u = (u + 0x7FFFu + ((u >> 16) & 1u)) >> 16;   // RNE
  return (u16)u;
}

__device__ __forceinline__ void acc8(float* a, s16x8 v) {
#pragma unroll
  for (int q = 0; q < 8; q++) a[q] += bf2f(v[q]);
}

__device__ __forceinline__ s16x8 pack8(const float* a) {
  s16x8 r;
#pragma unroll
  for (int q = 0; q < 8; q++) r[q] = (short)f2bf(a[q]);
  return r;
}

// Aggregate 128 contiguous bf16 feats (4 chunks of 8 per lane, lane offset
// `off`) over one CSR segment into a[4][8] fp32. 2-edge unroll for MLP.
template <int STRIDE>
__device__ __forceinline__ void gather128(const u16* __restrict__ buf, int off,
                                          const int* __restrict__ ssrc,
                                          int st, int cn, float a[4][8]) {
#pragma unroll
  for (int kk = 0; kk < 4; kk++)
#pragma unroll
    for (int q = 0; q < 8; q++) a[kk][q] = 0.f;
  int j = 0;
  for (; j + 1 < cn; j += 2) {
    int s0 = ssrc[st + j];
    int s1 = ssrc[st + j + 1];
    const u16* p0 = buf + s0 * STRIDE + off;
    const u16* p1 = buf + s1 * STRIDE + off;
    s16x8 v0[4], v1[4];
#pragma unroll
    for (int kk = 0; kk < 4; kk++) v0[kk] = *(const s16x8*)(p0 + kk * 32);
#pragma unroll
    for (int kk = 0; kk < 4; kk++) v1[kk] = *(const s16x8*)(p1 + kk * 32);
#pragma unroll
    for (int kk = 0; kk < 4; kk++) { acc8(a[kk], v0[kk]); acc8(a[kk], v1[kk]); }
  }
  if (j < cn) {
    int s0 = ssrc[st + j];
    const u16* p0 = buf + s0 * STRIDE + off;
#pragma unroll
    for (int kk = 0; kk < 4; kk++) {
      s16x8 v = *(const s16x8*)(p0 + kk * 32);
      acc8(a[kk], v);
    }
  }
}

// ---------------- prep ----------------

__global__ void k_castx(const float* __restrict__ x, u16* __restrict__ xb) {
  int i = blockIdx.x * 256 + threadIdx.x;
  if (i < NN * DD) xb[i] = f2bf(x[i]);
}

__global__ void k_wt1(const float* __restrict__ Wc1, const float* __restrict__ Ws1,
                      u16* __restrict__ Wt1) {
  int i = blockIdx.x * 256 + threadIdx.x;
  if (i >= HH * K1) return;
  int o = i / K1, k = i - o * K1;
  float v = (k < CC * DD) ? Wc1[(k >> 7) * (HH * DD) + o * DD + (k & 127)]
                          : Ws1[o * DD + (k - CC * DD)];
  Wt1[i] = f2bf(v);
}

__global__ void k_wt2(const float* __restrict__ Wc2, const float* __restrict__ Ws2,
                      u16* __restrict__ Wt2) {
  int i = blockIdx.x * 256 + threadIdx.x;
  if (i >= DD * K2) return;
  int o = i / K2, k = i - o * K2;
  float v = (k < CC * HH) ? Wc2[(k >> 8) * (DD * HH) + o * HH + (k & 255)]
                          : Ws2[o * HH + (k - CC * HH)];
  Wt2[i] = f2bf(v);
}

// ---------------- CSR build over seg = c*N + dst ----------------

__global__ void k_hist(const int* __restrict__ ei, const int* __restrict__ ec,
                       int* __restrict__ counts) {
  int e = blockIdx.x * 256 + threadIdx.x;
  if (e < EE) {
    int dst = ei[EE + e];
    int c = ec[e];
    atomicAdd(&counts[c * NN + dst], 1);
  }
}

__global__ void k_offsets(const int* __restrict__ counts, int2* __restrict__ oc,
                          int* __restrict__ cursor, int* __restrict__ gcount) {
  __shared__ int lds[256];
  __shared__ int basesh;
  int tid = threadIdx.x;
  int i = blockIdx.x * 256 + tid;
  int c = (i < CC * NN) ? counts[i] : 0;
  lds[tid] = c;
  __syncthreads();
  int v = c;
  for (int s = 1; s < 256; s <<= 1) {
    int t = (tid >= s) ? lds[tid - s] : 0;
    __syncthreads();
    v += t;
    lds[tid] = v;
    __syncthreads();
  }
  if (tid == 255) basesh = atomicAdd(gcount, v);
  __syncthreads();
  int excl = basesh + v - c;
  if (i < CC * NN) {
    oc[i] = make_int2(excl, c);
    cursor[i] = excl;
  }
}

__global__ void k_fill(const int* __restrict__ ei, const int* __restrict__ ec,
                       int* __restrict__ cursor, int* __restrict__ ssrc) {
  int e = blockIdx.x * 256 + threadIdx.x;
  if (e < EE) {
    int src = ei[e];
    int dst = ei[EE + e];
    int seg = ec[e] * NN + dst;
    int slot = atomicAdd(&cursor[seg], 1);
    ssrc[slot] = src;
  }
}

// ---------------- fused gather + GEMM layers ----------------
// Wave owns 16 rows x full output width. A-frag: row = lane&15, k = 8*(lane>>4)+j.
// B-frag: col = lane&15, k = 8*(lane>>4)+j (Wt[o][k]). C/D: col = lane&15,
// row = (lane>>4)*4 + reg.

__global__ void __launch_bounds__(256) k_gemm1(
    const u16* __restrict__ xb, const u16* __restrict__ Wt,
    const float* __restrict__ b1,
    const int2* __restrict__ oc, const int* __restrict__ ssrc,
    u16* __restrict__ hb) {
  int wid = blockIdx.x * 4 + (threadIdx.x >> 6);
  int lane = threadIdx.x & 63;
  int r0 = wid * 16;
  if (r0 >= NN) return;
  int rs = lane & 15;
  int kg = lane >> 4;
  int row = r0 + rs;
  int off = kg * 8;

  f32x4 acc[16];
#pragma unroll
  for (int i = 0; i < 16; i++)
#pragma unroll
    for (int q = 0; q < 4; q++) acc[i][q] = 0.f;

  for (int c = 0; c < CC; ++c) {
    int2 se = oc[c * NN + row];
    float a[4][8];
    gather128<DD>(xb, off, ssrc, se.x, se.y, a);
#pragma unroll
    for (int kk = 0; kk < 4; ++kk) {
      s16x8 af = pack8(a[kk]);
      int k0 = c * 128 + kk * 32;
#pragma unroll
      for (int fc = 0; fc < 16; ++fc) {
        int col = fc * 16 + rs;
        s16x8 bfr = *(const s16x8*)(Wt + col * K1 + k0 + off);
        acc[fc] = __builtin_amdgcn_mfma_f32_16x16x32_bf16(af, bfr, acc[fc], 0, 0, 0);
      }
    }
  }
  // self block
#pragma unroll
  for (int kk = 0; kk < 4; ++kk) {
    s16x8 af = *(const s16x8*)(xb + row * DD + kk * 32 + off);
    int k0 = CC * DD + kk * 32;
#pragma unroll
    for (int fc = 0; fc < 16; ++fc) {
      int col = fc * 16 + rs;
      s16x8 bfr = *(const s16x8*)(Wt + col * K1 + k0 + off);
      acc[fc] = __builtin_amdgcn_mfma_f32_16x16x32_bf16(af, bfr, acc[fc], 0, 0, 0);
    }
  }

#pragma unroll
  for (int fc = 0; fc < 16; ++fc) {
    int col = fc * 16 + rs;
    float bias = b1[col];
#pragma unroll
    for (int q = 0; q < 4; ++q) {
      float v = acc[fc][q] + bias;
      if (v < 0.f) v = 0.f;
      int rr = r0 + kg * 4 + q;
      hb[rr * HH + col] = f2bf(v);
    }
  }
}

__global__ void __launch_bounds__(256) k_gemm2(
    const u16* __restrict__ hb, const u16* __restrict__ Wt,
    const float* __restrict__ b2,
    const int2* __restrict__ oc, const int* __restrict__ ssrc,
    float* __restrict__ out) {
  int wid = blockIdx.x * 4 + (threadIdx.x >> 6);
  int lane = threadIdx.x & 63;
  int r0 = wid * 16;
  if (r0 >= NN) return;
  int rs = lane & 15;
  int kg = lane >> 4;
  int row = r0 + rs;
  int off = kg * 8;

  f32x4 acc[8];
#pragma unroll
  for (int i = 0; i < 8; i++)
#pragma unroll
    for (int q = 0; q < 4; q++) acc[i][q] = 0.f;

  for (int c = 0; c < CC; ++c) {
    int2 se = oc[c * NN + row];
#pragma unroll
    for (int h = 0; h < 2; ++h) {
      float a[4][8];
      gather128<HH>(hb, h * 128 + off, ssrc, se.x, se.y, a);
#pragma unroll
      for (int kk = 0; kk < 4; ++kk) {
        s16x8 af = pack8(a[kk]);
        int k0 = c * 256 + h * 128 + kk * 32;
#pragma unroll
        for (int fc = 0; fc < 8; ++fc) {
          int col = fc * 16 + rs;
          s16x8 bfr = *(const s16x8*)(Wt + col * K2 + k0 + off);
          acc[fc] = __builtin_amdgcn_mfma_f32_16x16x32_bf16(af, bfr, acc[fc], 0, 0, 0);
        }
      }
    }
  }
  // self block
#pragma unroll
  for (int kk = 0; kk < 8; ++kk) {
    s16x8 af = *(const s16x8*)(hb + row * HH + kk * 32 + off);
    int k0 = CC * HH + kk * 32;
#pragma unroll
    for (int fc = 0; fc < 8; ++fc) {
      int col = fc * 16 + rs;
      s16x8 bfr = *(const s16x8*)(Wt + col * K2 + k0 + off);
      acc[fc] = __builtin_amdgcn_mfma_f32_16x16x32_bf16(af, bfr, acc[fc], 0, 0, 0);
    }
  }

#pragma unroll
  for (int fc = 0; fc < 8; ++fc) {
    int col = fc * 16 + rs;
    float bias = b2[col];
#pragma unroll
    for (int q = 0; q < 4; ++q) {
      float v = acc[fc][q] + bias;
      int rr = r0 + kg * 4 + q;
      out[rr * DD + col] = 1.f / (1.f + expf(10.f - v));
    }
  }
}

// ---------------- launch ----------------

extern "C" void kernel_launch(void* const* d_in, const int* in_sizes, int n_in,
                              void* d_out, int out_size, void* d_ws, size_t ws_size,
                              hipStream_t stream) {
  const float* x   = (const float*)d_in[0];
  const int*   ei  = (const int*)d_in[1];
  const int*   ec  = (const int*)d_in[2];
  const float* Ws1 = (const float*)d_in[3];
  const float* b1  = (const float*)d_in[4];
  const float* Ws2 = (const float*)d_in[5];
  const float* b2  = (const float*)d_in[6];
  const float* Wc1 = (const float*)d_in[7];
  const float* Wc2 = (const float*)d_in[8];
  float* out = (float*)d_out;

  char* p = (char*)d_ws;
  u16*  xb     = (u16*)p;  p += 12800000;   // x bf16 [N,128]
  u16*  Wt1    = (u16*)p;  p += 589824;     // [256,1152] bf16
  u16*  Wt2    = (u16*)p;  p += 589824;     // [128,2304] bf16
  int*  counts = (int*)p;  p += 1600000;    // [C*N]
  int*  gcount = (int*)p;  p += 256;
  int2* oc     = (int2*)p; p += 3200000;    // [C*N] {off, cnt}
  int*  cursor = (int*)p;  p += 1600000;    // [C*N]
  int*  ssrc   = (int*)p;  p += 3200000;    // [E]
  u16*  hb     = (u16*)p;  p += 25600000;   // h bf16 [N,256]

  hipMemsetAsync(counts, 0, 1600000 + 256, stream);  // counts + gcount

  k_castx<<<25000, 256, 0, stream>>>(x, xb);
  k_wt1<<<1152, 256, 0, stream>>>(Wc1, Ws1, Wt1);
  k_wt2<<<1152, 256, 0, stream>>>(Wc2, Ws2, Wt2);

  k_hist<<<3125, 256, 0, stream>>>(ei, ec, counts);
  k_offsets<<<1563, 256, 0, stream>>>(counts, oc, cursor, gcount);
  k_fill<<<3125, 256, 0, stream>>>(ei, ec, cursor, ssrc);

  k_gemm1<<<782, 256, 0, stream>>>(xb, Wt1, b1, oc, ssrc, hb);
  k_gemm2<<<782, 256, 0, stream>>>(hb, Wt2, b2, oc, ssrc, out);
}

// Round 7
// 728.575 us; speedup vs baseline: 1.2565x; 1.1001x over previous
//
#include <hip/hip_runtime.h>

// GNN: 2-layer edge-coloured conv on MI355X.
// Round 7 (= round 5 resubmit; infra failures r2/r3/r5/r6): block-cooperative
// LDS-staged gather. Per colour: 256 threads walk one (segment, 32B-chunk)
// each (coalesced per-edge reads, massive MLP), XOR-swizzled LDS, barrier,
// MFMA from LDS. 32-row blocks, grid 1563.

#define NN 50000
#define EE 800000
#define DD 128
#define HH 256
#define CC 8
#define K1 1152   // C*D + D
#define K2 2304   // C*H + H

typedef unsigned short u16;
typedef __attribute__((ext_vector_type(8))) short s16x8;
typedef __attribute__((ext_vector_type(4))) float f32x4;

__device__ __forceinline__ float bf2f(short u) {
  return __uint_as_float(((unsigned)(u16)u) << 16);
}
__device__ __forceinline__ u16 f2bf(float f) {
  unsigned u = __float_as_uint(f);
  u = (u + 0x7FFFu + ((u >> 16) & 1u)) >> 16;   // RNE
  return (u16)u;
}

// One thread aggregates a 32B (16-elt) chunk of one CSR segment into s[16].
// 4-deep ssrc prefetch; payload loads independent (2x16B per edge).
__device__ __forceinline__ void gather32B(const u16* __restrict__ src, int stride,
                                          const int* __restrict__ ssrc,
                                          int st, int cn, int eoff, float* s) {
#pragma unroll
  for (int q = 0; q < 16; q++) s[q] = 0.f;
  for (int j = 0; j < cn; j += 4) {
    int idx[4];
#pragma unroll
    for (int t = 0; t < 4; t++) idx[t] = (j + t < cn) ? ssrc[st + j + t] : -1;
#pragma unroll
    for (int t = 0; t < 4; t++) {
      if (idx[t] >= 0) {
        const u16* pp = src + (size_t)idx[t] * stride + eoff;
        s16x8 lo = *(const s16x8*)pp;
        s16x8 hi = *(const s16x8*)(pp + 8);
#pragma unroll
        for (int q = 0; q < 8; q++) s[q] += bf2f(lo[q]);
#pragma unroll
        for (int q = 0; q < 8; q++) s[q + 8] += bf2f(hi[q]);
      }
    }
  }
}

__device__ __forceinline__ void lds_put32(char* As, unsigned base, unsigned swz,
                                          const float* s) {
  s16x8 lo, hi;
#pragma unroll
  for (int q = 0; q < 8; q++) lo[q] = (short)f2bf(s[q]);
#pragma unroll
  for (int q = 0; q < 8; q++) hi[q] = (short)f2bf(s[q + 8]);
  *(s16x8*)(As + (base ^ swz)) = lo;
  *(s16x8*)(As + ((base + 16) ^ swz)) = hi;
}

// ---------------- prep ----------------

__global__ void k_castx(const float* __restrict__ x, u16* __restrict__ xb) {
  int i = blockIdx.x * 256 + threadIdx.x;
  if (i < NN * DD) xb[i] = f2bf(x[i]);
}

__global__ void k_wt1(const float* __restrict__ Wc1, const float* __restrict__ Ws1,
                      u16* __restrict__ Wt1) {
  int i = blockIdx.x * 256 + threadIdx.x;
  if (i >= HH * K1) return;
  int o = i / K1, k = i - o * K1;
  float v = (k < CC * DD) ? Wc1[(k >> 7) * (HH * DD) + o * DD + (k & 127)]
                          : Ws1[o * DD + (k - CC * DD)];
  Wt1[i] = f2bf(v);
}

__global__ void k_wt2(const float* __restrict__ Wc2, const float* __restrict__ Ws2,
                      u16* __restrict__ Wt2) {
  int i = blockIdx.x * 256 + threadIdx.x;
  if (i >= DD * K2) return;
  int o = i / K2, k = i - o * K2;
  float v = (k < CC * HH) ? Wc2[(k >> 8) * (DD * HH) + o * HH + (k & 255)]
                          : Ws2[o * HH + (k - CC * HH)];
  Wt2[i] = f2bf(v);
}

// ---------------- CSR build over seg = c*N + dst ----------------

__global__ void k_hist(const int* __restrict__ ei, const int* __restrict__ ec,
                       int* __restrict__ counts) {
  int e = blockIdx.x * 256 + threadIdx.x;
  if (e < EE) {
    int dst = ei[EE + e];
    int c = ec[e];
    atomicAdd(&counts[c * NN + dst], 1);
  }
}

__global__ void k_offsets(const int* __restrict__ counts, int2* __restrict__ oc,
                          int* __restrict__ cursor, int* __restrict__ gcount) {
  __shared__ int lds[256];
  __shared__ int basesh;
  int tid = threadIdx.x;
  int i = blockIdx.x * 256 + tid;
  int c = (i < CC * NN) ? counts[i] : 0;
  lds[tid] = c;
  __syncthreads();
  int v = c;
  for (int s = 1; s < 256; s <<= 1) {
    int t = (tid >= s) ? lds[tid - s] : 0;
    __syncthreads();
    v += t;
    lds[tid] = v;
    __syncthreads();
  }
  if (tid == 255) basesh = atomicAdd(gcount, v);
  __syncthreads();
  int excl = basesh + v - c;
  if (i < CC * NN) {
    oc[i] = make_int2(excl, c);
    cursor[i] = excl;
  }
}

__global__ void k_fill(const int* __restrict__ ei, const int* __restrict__ ec,
                       int* __restrict__ cursor, int* __restrict__ ssrc) {
  int e = blockIdx.x * 256 + threadIdx.x;
  if (e < EE) {
    int src = ei[e];
    int dst = ei[EE + e];
    int seg = ec[e] * NN + dst;
    int slot = atomicAdd(&cursor[seg], 1);
    ssrc[slot] = src;
  }
}

// ---------------- fused LDS-staged gather + GEMM ----------------
// Block: 256 threads, 32 rows. Wave w: row-tile rt=w>>1 (16 rows), col-half
// ch=w&1. Per colour: cooperative gather into LDS (thread = (seg,chunk32B)),
// swizzle byte^=(row&7)<<4; barrier; MFMA from LDS; barrier.
// A-frag: row=lane&15, k=8*(lane>>4)+j. C/D: col=lane&15, row=(lane>>4)*4+reg.

__global__ void __launch_bounds__(256) k_gemm1(
    const u16* __restrict__ xb, const u16* __restrict__ Wt,
    const float* __restrict__ b1,
    const int2* __restrict__ oc, const int* __restrict__ ssrc,
    u16* __restrict__ hb) {
  __shared__ char As[32 * 256];           // 32 rows x 128 feats bf16 = 8KB
  int tid = threadIdx.x;
  int w = tid >> 6, lane = tid & 63;
  int rs = lane & 15, kg = lane >> 4;
  int rt = w >> 1, ch = w & 1;
  int r0 = blockIdx.x * 32;
  int rowl = rt * 16 + rs;                // MFMA A row (block-local)
  unsigned swzr = (rowl & 7) << 4;
  int rowL = min(r0 + rowl, NN - 1);
  // gather assignment: 32 segs x 8 chunks = 256 items = 1/thread
  int gseg = tid >> 3, gchunk = tid & 7;
  int grow = r0 + gseg;
  unsigned gbase = gseg * 256 + gchunk * 32;
  unsigned gswz = (gseg & 7) << 4;

  f32x4 acc[8];
#pragma unroll
  for (int i = 0; i < 8; i++)
#pragma unroll
    for (int q = 0; q < 4; q++) acc[i][q] = 0.f;

  for (int c = 0; c < CC; ++c) {
    int2 se = (grow < NN) ? oc[c * NN + grow] : make_int2(0, 0);
    float s[16];
    gather32B(xb, DD, ssrc, se.x, se.y, gchunk * 16, s);
    lds_put32(As, gbase, gswz, s);
    __syncthreads();
#pragma unroll
    for (int kk = 0; kk < 4; ++kk) {
      unsigned L = rowl * 256 + kk * 64 + kg * 16;
      s16x8 af = *(const s16x8*)(As + (L ^ swzr));
      int k0 = c * 128 + kk * 32;
#pragma unroll
      for (int fc = 0; fc < 8; ++fc) {
        int col = ch * 128 + fc * 16 + rs;
        s16x8 bfr = *(const s16x8*)(Wt + col * K1 + k0 + kg * 8);
        acc[fc] = __builtin_amdgcn_mfma_f32_16x16x32_bf16(af, bfr, acc[fc], 0, 0, 0);
      }
    }
    __syncthreads();
  }
  // self block (A = x, direct from global)
#pragma unroll
  for (int kk = 0; kk < 4; ++kk) {
    s16x8 af = *(const s16x8*)(xb + rowL * DD + kk * 32 + kg * 8);
    int k0 = CC * DD + kk * 32;
#pragma unroll
    for (int fc = 0; fc < 8; ++fc) {
      int col = ch * 128 + fc * 16 + rs;
      s16x8 bfr = *(const s16x8*)(Wt + col * K1 + k0 + kg * 8);
      acc[fc] = __builtin_amdgcn_mfma_f32_16x16x32_bf16(af, bfr, acc[fc], 0, 0, 0);
    }
  }
#pragma unroll
  for (int fc = 0; fc < 8; ++fc) {
    int col = ch * 128 + fc * 16 + rs;
    float bias = b1[col];
#pragma unroll
    for (int q = 0; q < 4; ++q) {
      float v = acc[fc][q] + bias;
      if (v < 0.f) v = 0.f;
      int rr = r0 + rt * 16 + kg * 4 + q;
      if (rr < NN) hb[rr * HH + col] = f2bf(v);
    }
  }
}

__global__ void __launch_bounds__(256) k_gemm2(
    const u16* __restrict__ hb, const u16* __restrict__ Wt,
    const float* __restrict__ b2,
    const int2* __restrict__ oc, const int* __restrict__ ssrc,
    float* __restrict__ out) {
  __shared__ char As[32 * 512];           // 32 rows x 256 feats bf16 = 16KB
  int tid = threadIdx.x;
  int w = tid >> 6, lane = tid & 63;
  int rs = lane & 15, kg = lane >> 4;
  int rt = w >> 1, ch = w & 1;
  int r0 = blockIdx.x * 32;
  int rowl = rt * 16 + rs;
  unsigned swzr = (rowl & 7) << 4;
  int rowL = min(r0 + rowl, NN - 1);

  f32x4 acc[4];
#pragma unroll
  for (int i = 0; i < 4; i++)
#pragma unroll
    for (int q = 0; q < 4; q++) acc[i][q] = 0.f;

  for (int c = 0; c < CC; ++c) {
    // gather: 32 segs x 16 chunks = 512 items = 2/thread
#pragma unroll
    for (int i = 0; i < 2; ++i) {
      int item = tid + i * 256;
      int gseg = item >> 4, gchunk = item & 15;
      int grow = r0 + gseg;
      int2 se = (grow < NN) ? oc[c * NN + grow] : make_int2(0, 0);
      float s[16];
      gather32B(hb, HH, ssrc, se.x, se.y, gchunk * 16, s);
      lds_put32(As, gseg * 512 + gchunk * 32, (gseg & 7) << 4, s);
    }
    __syncthreads();
#pragma unroll
    for (int kk = 0; kk < 8; ++kk) {
      unsigned L = rowl * 512 + kk * 64 + kg * 16;
      s16x8 af = *(const s16x8*)(As + (L ^ swzr));
      int k0 = c * 256 + kk * 32;
#pragma unroll
      for (int fc = 0; fc < 4; ++fc) {
        int col = ch * 64 + fc * 16 + rs;
        s16x8 bfr = *(const s16x8*)(Wt + col * K2 + k0 + kg * 8);
        acc[fc] = __builtin_amdgcn_mfma_f32_16x16x32_bf16(af, bfr, acc[fc], 0, 0, 0);
      }
    }
    __syncthreads();
  }
  // self block (A = h, direct from global)
#pragma unroll
  for (int kk = 0; kk < 8; ++kk) {
    s16x8 af = *(const s16x8*)(hb + rowL * HH + kk * 32 + kg * 8);
    int k0 = CC * HH + kk * 32;
#pragma unroll
    for (int fc = 0; fc < 4; ++fc) {
      int col = ch * 64 + fc * 16 + rs;
      s16x8 bfr = *(const s16x8*)(Wt + col * K2 + k0 + kg * 8);
      acc[fc] = __builtin_amdgcn_mfma_f32_16x16x32_bf16(af, bfr, acc[fc], 0, 0, 0);
    }
  }
#pragma unroll
  for (int fc = 0; fc < 4; ++fc) {
    int col = ch * 64 + fc * 16 + rs;
    float bias = b2[col];
#pragma unroll
    for (int q = 0; q < 4; ++q) {
      float v = acc[fc][q] + bias;
      int rr = r0 + rt * 16 + kg * 4 + q;
      if (rr < NN) out[rr * DD + col] = 1.f / (1.f + expf(10.f - v));
    }
  }
}

// ---------------- launch ----------------

extern "C" void kernel_launch(void* const* d_in, const int* in_sizes, int n_in,
                              void* d_out, int out_size, void* d_ws, size_t ws_size,
                              hipStream_t stream) {
  const float* x   = (const float*)d_in[0];
  const int*   ei  = (const int*)d_in[1];
  const int*   ec  = (const int*)d_in[2];
  const float* Ws1 = (const float*)d_in[3];
  const float* b1  = (const float*)d_in[4];
  const float* Ws2 = (const float*)d_in[5];
  const float* b2  = (const float*)d_in[6];
  const float* Wc1 = (const float*)d_in[7];
  const float* Wc2 = (const float*)d_in[8];
  float* out = (float*)d_out;

  char* p = (char*)d_ws;
  u16*  xb     = (u16*)p;  p += 12800000;   // x bf16 [N,128]
  u16*  Wt1    = (u16*)p;  p += 589824;     // [256,1152] bf16
  u16*  Wt2    = (u16*)p;  p += 589824;     // [128,2304] bf16
  int*  counts = (int*)p;  p += 1600000;    // [C*N]
  int*  gcount = (int*)p;  p += 256;
  int2* oc     = (int2*)p; p += 3200000;    // [C*N] {off, cnt}
  int*  cursor = (int*)p;  p += 1600000;    // [C*N]
  int*  ssrc   = (int*)p;  p += 3200000;    // [E]
  u16*  hb     = (u16*)p;  p += 25600000;   // h bf16 [N,256]

  hipMemsetAsync(counts, 0, 1600000 + 256, stream);  // counts + gcount

  k_castx<<<25000, 256, 0, stream>>>(x, xb);
  k_wt1<<<1152, 256, 0, stream>>>(Wc1, Ws1, Wt1);
  k_wt2<<<1152, 256, 0, stream>>>(Wc2, Ws2, Wt2);

  k_hist<<<3125, 256, 0, stream>>>(ei, ec, counts);
  k_offsets<<<1563, 256, 0, stream>>>(counts, oc, cursor, gcount);
  k_fill<<<3125, 256, 0, stream>>>(ei, ec, cursor, ssrc);

  k_gemm1<<<1563, 256, 0, stream>>>(xb, Wt1, b1, oc, ssrc, hb);
  k_gemm2<<<1563, 256, 0, stream>>>(hb, Wt2, b2, oc, ssrc, out);
}